// Round 18
// baseline (156.275 us; speedup 1.0000x reference)
//
#include <hip/hip_runtime.h>

constexpr int PPB = 16;  // consecutive points per block (8192 blocks)
constexpr int GRP = 4;   // points per LDS buffer (15408 B); 2 buffers = 30.8 KB
constexpr int NG  = PPB / GRP;
constexpr int N56 = 56*56*64;    // 200704
constexpr int N28 = 28*28*128;   // 100352
constexpr int N14 = 14*14*256;   //  50176
constexpr int N7  = 7*7*512;     //  25088
constexpr int NTOT = N56 + N28 + N14 + N7;       // 376320
constexpr int CONV_BLOCKS = (NTOT + 255) / 256;  // 1470

typedef float    f4v __attribute__((ext_vector_type(4)));
typedef _Float16 h4v __attribute__((ext_vector_type(4)));

// LDS-only barrier: drain LDS ops but leave stores / gathers in flight.
__device__ __forceinline__ void lds_barrier() {
    asm volatile("s_waitcnt lgkmcnt(0)" ::: "memory");
    __builtin_amdgcn_s_barrier();
    asm volatile("" ::: "memory");
}

// ---- fp32 features -> fp16 in d_ws ----
__global__ __launch_bounds__(256) void convert_feats_kernel(
    const float* __restrict__ f56, const float* __restrict__ f28,
    const float* __restrict__ f14, const float* __restrict__ f7,
    _Float16* __restrict__ ws)
{
    int idx = blockIdx.x * 256 + threadIdx.x;
    if (idx >= NTOT) return;
    float v;
    if (idx < N56)              v = f56[idx];
    else if (idx < N56+N28)     v = f28[idx - N56];
    else if (idx < N56+N28+N14) v = f14[idx - (N56+N28)];
    else                        v = f7[idx - (N56+N28+N14)];
    ws[idx] = (_Float16)v;
}

// compute GRP points' rows into one LDS buffer (this thread's channel quad)
__device__ __forceinline__ void compute_group(
    int pg, int n, int t, int ch,
    const float* __restrict__ coord,
    const _Float16* __restrict__ f, int C, int H, float inv,
    float* __restrict__ buf)
{
    #pragma unroll
    for (int k = 0; k < GRP; ++k) {
        const int p = pg + k;
        if (p >= n) break;

        const float X = coord[p * 3 + 0];
        const float Y = coord[p * 3 + 1];
        const float Z = coord[p * 3 + 2];

        const float rz = 1.0f / (-Z);
        float h = 250.0f * (-Y) * rz + 112.0f;
        float w = 250.0f * X  * rz + 112.0f;
        h = fminf(fmaxf(h, 0.0f), 223.0f);
        w = fminf(fmaxf(w, 0.0f), 223.0f);

        if (t < 240) {
            const float x = h * inv, y = w * inv;
            const float x1 = floorf(x), x2 = ceilf(x);
            const float y1 = floorf(y), y2 = ceilf(y);
            const int xi1 = min(max((int)x1, 0), H - 1);
            const int xi2 = min(max((int)x2, 0), H - 1);
            const int yi1 = min(max((int)y1, 0), H - 1);
            const int yi2 = min(max((int)y2, 0), H - 1);
            const float w11 = (x2 - x) * (y2 - y);
            const float w21 = (x - x1) * (y2 - y);
            const float w12 = (x2 - x) * (y - y1);
            const float w22 = (x - x1) * (y - y1);

            const int r1 = xi1 * H, r2 = xi2 * H;
            const h4v a = *reinterpret_cast<const h4v*>(f + (r1 + yi1) * C);
            const h4v b = *reinterpret_cast<const h4v*>(f + (r2 + yi1) * C);
            const h4v d = *reinterpret_cast<const h4v*>(f + (r1 + yi2) * C);
            const h4v e = *reinterpret_cast<const h4v*>(f + (r2 + yi2) * C);

            float* dst = buf + k * 963 + 3 + ch;
            dst[0] = w11*(float)a.x + w21*(float)b.x + w12*(float)d.x + w22*(float)e.x;
            dst[1] = w11*(float)a.y + w21*(float)b.y + w12*(float)d.y + w22*(float)e.y;
            dst[2] = w11*(float)a.z + w21*(float)b.z + w12*(float)d.z + w22*(float)e.z;
            dst[3] = w11*(float)a.w + w21*(float)b.w + w12*(float)d.w + w22*(float)e.w;
        } else if (t < 243) {
            buf[k * 963 + (t - 240)] = coord[p * 3 + (t - 240)];
        }
    }
}

// flush one buffer (GRP rows, 15408 B contiguous) as aligned NORMAL float4
// burst (write-allocate; A/B vs R15's nt — fills get 6.9 TB/s this way)
__device__ __forceinline__ void flush_group(
    const float* __restrict__ buf, float* __restrict__ dst_base, int t)
{
    const f4v* __restrict__ s4 = reinterpret_cast<const f4v*>(buf);
    f4v* __restrict__ d4 = reinterpret_cast<f4v*>(dst_base);
    #pragma unroll
    for (int i = t; i < GRP * 963 / 4; i += 256)   // 963 float4s
        d4[i] = s4[i];
}

// ---- hot kernel: double-buffered, flush-first, LDS-only barriers ----
__global__ __launch_bounds__(256) void GraphProjection_57483842289710_kernel(
    const float* __restrict__ coord,
    const _Float16* __restrict__ ws,
    float* __restrict__ out, int n)
{
    __shared__ float lds[2][GRP * 963];   // 2 x 15408 B

    const int t = threadIdx.x;
    const int ch = 4 * t;
    const _Float16* f; int C, H; float inv;
    if (ch < 64)       { f = ws + ch;                     C = 64;  H = 56; inv = 0.25f;    }
    else if (ch < 192) { f = ws + N56 + (ch - 64);        C = 128; H = 28; inv = 0.125f;   }
    else if (ch < 448) { f = ws + N56+N28 + (ch - 192);   C = 256; H = 14; inv = 0.0625f;  }
    else               { f = ws + N56+N28+N14 + (ch-448); C = 512; H = 7;  inv = 0.03125f; }

    const int p0 = blockIdx.x * PPB;

    // prologue: compute group 0
    compute_group(p0, n, t, ch, coord, f, C, H, inv, lds[0]);
    lds_barrier();

    // steady state: flush group g-1, compute group g under the draining stores
    for (int g = 1; g < NG; ++g) {
        flush_group(lds[(g - 1) & 1], out + (size_t)(p0 + (g - 1) * GRP) * 963, t);
        compute_group(p0 + g * GRP, n, t, ch, coord, f, C, H, inv, lds[g & 1]);
        lds_barrier();
    }

    // epilogue: flush last group
    flush_group(lds[(NG - 1) & 1], out + (size_t)(p0 + (NG - 1) * GRP) * 963, t);
}

// ---- fp32 fallback (round-4 winner) if ws too small ----
__global__ __launch_bounds__(256) void proj_f32_kernel(
    const float* __restrict__ coord,
    const float* __restrict__ f56, const float* __restrict__ f28,
    const float* __restrict__ f14, const float* __restrict__ f7,
    float* __restrict__ out, int n)
{
    const int t = threadIdx.x;
    const int ch = 4 * t;
    const float* f; int C, H; float inv;
    if (ch < 64)       { f = f56 + ch;         C = 64;  H = 56; inv = 0.25f;    }
    else if (ch < 192) { f = f28 + (ch - 64);  C = 128; H = 28; inv = 0.125f;   }
    else if (ch < 448) { f = f14 + (ch - 192); C = 256; H = 14; inv = 0.0625f;  }
    else               { f = f7  + (ch - 448); C = 512; H = 7;  inv = 0.03125f; }
    const int p0 = blockIdx.x * 16, pend = min(p0 + 16, n);
    #pragma unroll 2
    for (int p = p0; p < pend; ++p) {
        float* __restrict__ orow = out + (size_t)p * 963;
        const float X = coord[p*3+0], Y = coord[p*3+1], Z = coord[p*3+2];
        const float rz = 1.0f / (-Z);
        float h = 250.0f * (-Y) * rz + 112.0f;
        float w = 250.0f * X  * rz + 112.0f;
        h = fminf(fmaxf(h, 0.0f), 223.0f);
        w = fminf(fmaxf(w, 0.0f), 223.0f);
        if (t < 240) {
            const float x = h * inv, y = w * inv;
            const float x1 = floorf(x), x2 = ceilf(x);
            const float y1 = floorf(y), y2 = ceilf(y);
            const int xi1 = min(max((int)x1, 0), H - 1);
            const int xi2 = min(max((int)x2, 0), H - 1);
            const int yi1 = min(max((int)y1, 0), H - 1);
            const int yi2 = min(max((int)y2, 0), H - 1);
            const float w11 = (x2-x)*(y2-y), w21 = (x-x1)*(y2-y);
            const float w12 = (x2-x)*(y-y1), w22 = (x-x1)*(y-y1);
            const int r1 = xi1*H, r2 = xi2*H;
            const float4 a = *reinterpret_cast<const float4*>(f + (r1+yi1)*C);
            const float4 b = *reinterpret_cast<const float4*>(f + (r2+yi1)*C);
            const float4 d = *reinterpret_cast<const float4*>(f + (r1+yi2)*C);
            const float4 e = *reinterpret_cast<const float4*>(f + (r2+yi2)*C);
            f4v r;
            r.x = w11*a.x + w21*b.x + w12*d.x + w22*e.x;
            r.y = w11*a.y + w21*b.y + w12*d.y + w22*e.y;
            r.z = w11*a.z + w21*b.z + w12*d.z + w22*e.z;
            r.w = w11*a.w + w21*b.w + w12*d.w + w22*e.w;
            *reinterpret_cast<f4v*>(orow + 3 + ch) = r;
        } else if (t < 243) {
            orow[t - 240] = coord[p*3 + (t-240)];
        }
    }
}

extern "C" void kernel_launch(void* const* d_in, const int* in_sizes, int n_in,
                              void* d_out, int out_size, void* d_ws, size_t ws_size,
                              hipStream_t stream) {
    const float* coord = (const float*)d_in[0];
    const float* f56   = (const float*)d_in[1];
    const float* f28   = (const float*)d_in[2];
    const float* f14   = (const float*)d_in[3];
    const float* f7    = (const float*)d_in[4];
    float* out = (float*)d_out;

    int n = in_sizes[0] / 3;  // 131072 points

    if (ws_size >= (size_t)NTOT * sizeof(_Float16)) {
        _Float16* ws = (_Float16*)d_ws;
        convert_feats_kernel<<<CONV_BLOCKS, 256, 0, stream>>>(f56, f28, f14, f7, ws);
        int grid = (n + PPB - 1) / PPB;  // 8192
        GraphProjection_57483842289710_kernel<<<grid, 256, 0, stream>>>(coord, ws, out, n);
    } else {
        int grid = (n + 15) / 16;
        proj_f32_kernel<<<grid, 256, 0, stream>>>(coord, f56, f28, f14, f7, out, n);
    }
}

// Round 19
// 130.661 us; speedup vs baseline: 1.1960x; 1.1960x over previous
//
#include <hip/hip_runtime.h>

constexpr int PPB = 16;  // consecutive points per block (8192 blocks)
constexpr int GRP = 4;   // points per LDS buffer (15408 B); 2 buffers = 30.8 KB
constexpr int NG  = PPB / GRP;
constexpr int N56 = 56*56*64;    // 200704
constexpr int N28 = 28*28*128;   // 100352
constexpr int N14 = 14*14*256;   //  50176
constexpr int N7  = 7*7*512;     //  25088
constexpr int NTOT = N56 + N28 + N14 + N7;       // 376320
constexpr int CONV_BLOCKS = (NTOT + 255) / 256;  // 1470

typedef float    f4v __attribute__((ext_vector_type(4)));
typedef float    f8v __attribute__((ext_vector_type(8)));
typedef _Float16 h8v __attribute__((ext_vector_type(8)));

// LDS-only barrier: drain LDS ops but leave nt stores / gathers in flight.
__device__ __forceinline__ void lds_barrier() {
    asm volatile("s_waitcnt lgkmcnt(0)" ::: "memory");
    __builtin_amdgcn_s_barrier();
    asm volatile("" ::: "memory");
}

// ---- fp32 features -> fp16 in d_ws ----
__global__ __launch_bounds__(256) void convert_feats_kernel(
    const float* __restrict__ f56, const float* __restrict__ f28,
    const float* __restrict__ f14, const float* __restrict__ f7,
    _Float16* __restrict__ ws)
{
    int idx = blockIdx.x * 256 + threadIdx.x;
    if (idx >= NTOT) return;
    float v;
    if (idx < N56)              v = f56[idx];
    else if (idx < N56+N28)     v = f28[idx - N56];
    else if (idx < N56+N28+N14) v = f14[idx - (N56+N28)];
    else                        v = f7[idx - (N56+N28+N14)];
    ws[idx] = (_Float16)v;
}

// compute GRP points into one LDS buffer. 2 point-teams of 128 threads
// (half = t>>7) -> setup runs on 2 waves/point instead of 4; each team
// thread owns 8 channels -> 16B fp16 gathers (half the VMEM instructions).
__device__ __forceinline__ void compute_group(
    int pg, int n, int t, int half, int tt, int ch,
    const float* __restrict__ coord,
    const _Float16* __restrict__ f, int C, int H, float inv,
    float* __restrict__ buf)
{
    #pragma unroll
    for (int k2 = 0; k2 < GRP / 2; ++k2) {
        const int k = 2 * k2 + half;
        const int p = pg + k;
        if (p >= n) continue;

        const float X = coord[p * 3 + 0];
        const float Y = coord[p * 3 + 1];
        const float Z = coord[p * 3 + 2];

        const float rz = 1.0f / (-Z);
        float h = 250.0f * (-Y) * rz + 112.0f;
        float w = 250.0f * X  * rz + 112.0f;
        h = fminf(fmaxf(h, 0.0f), 223.0f);
        w = fminf(fmaxf(w, 0.0f), 223.0f);

        if (tt < 120) {
            const float x = h * inv, y = w * inv;
            const float x1 = floorf(x), x2 = ceilf(x);
            const float y1 = floorf(y), y2 = ceilf(y);
            const int xi1 = min(max((int)x1, 0), H - 1);
            const int xi2 = min(max((int)x2, 0), H - 1);
            const int yi1 = min(max((int)y1, 0), H - 1);
            const int yi2 = min(max((int)y2, 0), H - 1);
            const float w11 = (x2 - x) * (y2 - y);
            const float w21 = (x - x1) * (y2 - y);
            const float w12 = (x2 - x) * (y - y1);
            const float w22 = (x - x1) * (y - y1);

            const int r1 = xi1 * H, r2 = xi2 * H;
            // 16B-aligned fp16 octo loads (ch multiple of 8)
            const h8v a = *reinterpret_cast<const h8v*>(f + (r1 + yi1) * C);
            const h8v b = *reinterpret_cast<const h8v*>(f + (r2 + yi1) * C);
            const h8v d = *reinterpret_cast<const h8v*>(f + (r1 + yi2) * C);
            const h8v e = *reinterpret_cast<const h8v*>(f + (r2 + yi2) * C);

            const f8v r = w11 * __builtin_convertvector(a, f8v)
                        + w21 * __builtin_convertvector(b, f8v)
                        + w12 * __builtin_convertvector(d, f8v)
                        + w22 * __builtin_convertvector(e, f8v);

            float* dst = buf + k * 963 + 3 + ch;
            #pragma unroll
            for (int j = 0; j < 8; ++j) dst[j] = r[j];
        } else if (tt < 123) {
            buf[k * 963 + (tt - 120)] = coord[p * 3 + (tt - 120)];
        }
    }
}

// flush one buffer (GRP rows, 15408 B contiguous) as aligned nt float4 burst
__device__ __forceinline__ void flush_group(
    const float* __restrict__ buf, float* __restrict__ dst_base, int t)
{
    const f4v* __restrict__ s4 = reinterpret_cast<const f4v*>(buf);
    f4v* __restrict__ d4 = reinterpret_cast<f4v*>(dst_base);
    #pragma unroll
    for (int i = t; i < GRP * 963 / 4; i += 256)   // 963 float4s
        __builtin_nontemporal_store(s4[i], d4 + i);
}

// ---- hot kernel: double-buffered, flush-first, LDS-only barriers,
//      2 point-teams x 8 channels/thread ----
__global__ __launch_bounds__(256) void GraphProjection_57483842289710_kernel(
    const float* __restrict__ coord,
    const _Float16* __restrict__ ws,
    float* __restrict__ out, int n)
{
    __shared__ float lds[2][GRP * 963];   // 2 x 15408 B

    const int t = threadIdx.x;
    const int half = t >> 7;          // point-team 0/1
    const int tt   = t & 127;
    const int ch   = 8 * tt;          // channels ch..ch+7 (960 = 120*8)

    const _Float16* f; int C, H; float inv;
    if (tt < 8)        { f = ws + ch;                     C = 64;  H = 56; inv = 0.25f;    }
    else if (tt < 24)  { f = ws + N56 + (ch - 64);        C = 128; H = 28; inv = 0.125f;   }
    else if (tt < 56)  { f = ws + N56+N28 + (ch - 192);   C = 256; H = 14; inv = 0.0625f;  }
    else               { f = ws + N56+N28+N14 + (ch-448); C = 512; H = 7;  inv = 0.03125f; }

    const int p0 = blockIdx.x * PPB;

    // prologue: compute group 0
    compute_group(p0, n, t, half, tt, ch, coord, f, C, H, inv, lds[0]);
    lds_barrier();

    // steady state: flush group g-1, compute group g under the draining stores
    for (int g = 1; g < NG; ++g) {
        flush_group(lds[(g - 1) & 1], out + (size_t)(p0 + (g - 1) * GRP) * 963, t);
        compute_group(p0 + g * GRP, n, t, half, tt, ch, coord, f, C, H, inv, lds[g & 1]);
        lds_barrier();
    }

    // epilogue: flush last group (stores drained by hardware at kernel end)
    flush_group(lds[(NG - 1) & 1], out + (size_t)(p0 + (NG - 1) * GRP) * 963, t);
}

// ---- fp32 fallback (round-4 winner) if ws too small ----
__global__ __launch_bounds__(256) void proj_f32_kernel(
    const float* __restrict__ coord,
    const float* __restrict__ f56, const float* __restrict__ f28,
    const float* __restrict__ f14, const float* __restrict__ f7,
    float* __restrict__ out, int n)
{
    const int t = threadIdx.x;
    const int ch = 4 * t;
    const float* f; int C, H; float inv;
    if (ch < 64)       { f = f56 + ch;         C = 64;  H = 56; inv = 0.25f;    }
    else if (ch < 192) { f = f28 + (ch - 64);  C = 128; H = 28; inv = 0.125f;   }
    else if (ch < 448) { f = f14 + (ch - 192); C = 256; H = 14; inv = 0.0625f;  }
    else               { f = f7  + (ch - 448); C = 512; H = 7;  inv = 0.03125f; }
    const int p0 = blockIdx.x * 16, pend = min(p0 + 16, n);
    #pragma unroll 2
    for (int p = p0; p < pend; ++p) {
        float* __restrict__ orow = out + (size_t)p * 963;
        const float X = coord[p*3+0], Y = coord[p*3+1], Z = coord[p*3+2];
        const float rz = 1.0f / (-Z);
        float h = 250.0f * (-Y) * rz + 112.0f;
        float w = 250.0f * X  * rz + 112.0f;
        h = fminf(fmaxf(h, 0.0f), 223.0f);
        w = fminf(fmaxf(w, 0.0f), 223.0f);
        if (t < 240) {
            const float x = h * inv, y = w * inv;
            const float x1 = floorf(x), x2 = ceilf(x);
            const float y1 = floorf(y), y2 = ceilf(y);
            const int xi1 = min(max((int)x1, 0), H - 1);
            const int xi2 = min(max((int)x2, 0), H - 1);
            const int yi1 = min(max((int)y1, 0), H - 1);
            const int yi2 = min(max((int)y2, 0), H - 1);
            const float w11 = (x2-x)*(y2-y), w21 = (x-x1)*(y2-y);
            const float w12 = (x2-x)*(y-y1), w22 = (x-x1)*(y-y1);
            const int r1 = xi1*H, r2 = xi2*H;
            const float4 a = *reinterpret_cast<const float4*>(f + (r1+yi1)*C);
            const float4 b = *reinterpret_cast<const float4*>(f + (r2+yi1)*C);
            const float4 d = *reinterpret_cast<const float4*>(f + (r1+yi2)*C);
            const float4 e = *reinterpret_cast<const float4*>(f + (r2+yi2)*C);
            f4v r;
            r.x = w11*a.x + w21*b.x + w12*d.x + w22*e.x;
            r.y = w11*a.y + w21*b.y + w12*d.y + w22*e.y;
            r.z = w11*a.z + w21*b.z + w12*d.z + w22*e.z;
            r.w = w11*a.w + w21*b.w + w12*d.w + w22*e.w;
            *reinterpret_cast<f4v*>(orow + 3 + ch) = r;
        } else if (t < 243) {
            orow[t - 240] = coord[p*3 + (t-240)];
        }
    }
}

extern "C" void kernel_launch(void* const* d_in, const int* in_sizes, int n_in,
                              void* d_out, int out_size, void* d_ws, size_t ws_size,
                              hipStream_t stream) {
    const float* coord = (const float*)d_in[0];
    const float* f56   = (const float*)d_in[1];
    const float* f28   = (const float*)d_in[2];
    const float* f14   = (const float*)d_in[3];
    const float* f7    = (const float*)d_in[4];
    float* out = (float*)d_out;

    int n = in_sizes[0] / 3;  // 131072 points

    if (ws_size >= (size_t)NTOT * sizeof(_Float16)) {
        _Float16* ws = (_Float16*)d_ws;
        convert_feats_kernel<<<CONV_BLOCKS, 256, 0, stream>>>(f56, f28, f14, f7, ws);
        int grid = (n + PPB - 1) / PPB;  // 8192
        GraphProjection_57483842289710_kernel<<<grid, 256, 0, stream>>>(coord, ws, out, n);
    } else {
        int grid = (n + 15) / 16;
        proj_f32_kernel<<<grid, 256, 0, stream>>>(coord, f56, f28, f14, f7, out, n);
    }
}

// Round 20
// 114.740 us; speedup vs baseline: 1.3620x; 1.1388x over previous
//
#include <hip/hip_runtime.h>

constexpr int PPB = 8;   // consecutive points per block (16384 blocks)
constexpr int GRP = 4;   // points per LDS buffer (15408 B); 2 buffers = 30.8 KB
constexpr int NG  = PPB / GRP;   // 2 groups/block
constexpr int N56 = 56*56*64;    // 200704
constexpr int N28 = 28*28*128;   // 100352
constexpr int N14 = 14*14*256;   //  50176
constexpr int N7  = 7*7*512;     //  25088
constexpr int NTOT = N56 + N28 + N14 + N7;       // 376320
constexpr int CONV_BLOCKS = (NTOT + 255) / 256;  // 1470

typedef float    f4v __attribute__((ext_vector_type(4)));
typedef _Float16 h4v __attribute__((ext_vector_type(4)));

// LDS-only barrier: drain LDS ops but leave nt stores / gathers in flight.
__device__ __forceinline__ void lds_barrier() {
    asm volatile("s_waitcnt lgkmcnt(0)" ::: "memory");
    __builtin_amdgcn_s_barrier();
    asm volatile("" ::: "memory");
}

// ---- fp32 features -> fp16 in d_ws ----
__global__ __launch_bounds__(256) void convert_feats_kernel(
    const float* __restrict__ f56, const float* __restrict__ f28,
    const float* __restrict__ f14, const float* __restrict__ f7,
    _Float16* __restrict__ ws)
{
    int idx = blockIdx.x * 256 + threadIdx.x;
    if (idx >= NTOT) return;
    float v;
    if (idx < N56)              v = f56[idx];
    else if (idx < N56+N28)     v = f28[idx - N56];
    else if (idx < N56+N28+N14) v = f14[idx - (N56+N28)];
    else                        v = f7[idx - (N56+N28+N14)];
    ws[idx] = (_Float16)v;
}

// compute GRP points' rows into one LDS buffer (this thread's channel quad)
__device__ __forceinline__ void compute_group(
    int pg, int n, int t, int ch,
    const float* __restrict__ coord,
    const _Float16* __restrict__ f, int C, int H, float inv,
    float* __restrict__ buf)
{
    #pragma unroll
    for (int k = 0; k < GRP; ++k) {
        const int p = pg + k;
        if (p >= n) break;

        const float X = coord[p * 3 + 0];
        const float Y = coord[p * 3 + 1];
        const float Z = coord[p * 3 + 2];

        const float rz = 1.0f / (-Z);
        float h = 250.0f * (-Y) * rz + 112.0f;
        float w = 250.0f * X  * rz + 112.0f;
        h = fminf(fmaxf(h, 0.0f), 223.0f);
        w = fminf(fmaxf(w, 0.0f), 223.0f);

        if (t < 240) {
            const float x = h * inv, y = w * inv;
            const float x1 = floorf(x), x2 = ceilf(x);
            const float y1 = floorf(y), y2 = ceilf(y);
            const int xi1 = min(max((int)x1, 0), H - 1);
            const int xi2 = min(max((int)x2, 0), H - 1);
            const int yi1 = min(max((int)y1, 0), H - 1);
            const int yi2 = min(max((int)y2, 0), H - 1);
            const float w11 = (x2 - x) * (y2 - y);
            const float w21 = (x - x1) * (y2 - y);
            const float w12 = (x2 - x) * (y - y1);
            const float w22 = (x - x1) * (y - y1);

            const int r1 = xi1 * H, r2 = xi2 * H;
            const h4v a = *reinterpret_cast<const h4v*>(f + (r1 + yi1) * C);
            const h4v b = *reinterpret_cast<const h4v*>(f + (r2 + yi1) * C);
            const h4v d = *reinterpret_cast<const h4v*>(f + (r1 + yi2) * C);
            const h4v e = *reinterpret_cast<const h4v*>(f + (r2 + yi2) * C);

            float* dst = buf + k * 963 + 3 + ch;
            dst[0] = w11*(float)a.x + w21*(float)b.x + w12*(float)d.x + w22*(float)e.x;
            dst[1] = w11*(float)a.y + w21*(float)b.y + w12*(float)d.y + w22*(float)e.y;
            dst[2] = w11*(float)a.z + w21*(float)b.z + w12*(float)d.z + w22*(float)e.z;
            dst[3] = w11*(float)a.w + w21*(float)b.w + w12*(float)d.w + w22*(float)e.w;
        } else if (t < 243) {
            buf[k * 963 + (t - 240)] = coord[p * 3 + (t - 240)];
        }
    }
}

// flush one buffer (GRP rows, 15408 B contiguous) as aligned nt float4 burst
__device__ __forceinline__ void flush_group(
    const float* __restrict__ buf, float* __restrict__ dst_base, int t)
{
    const f4v* __restrict__ s4 = reinterpret_cast<const f4v*>(buf);
    f4v* __restrict__ d4 = reinterpret_cast<f4v*>(dst_base);
    #pragma unroll
    for (int i = t; i < GRP * 963 / 4; i += 256)   // 963 float4s
        __builtin_nontemporal_store(s4[i], d4 + i);
}

// ---- hot kernel: double-buffered, flush-first, LDS-only barriers, PPB=8 ----
__global__ __launch_bounds__(256) void GraphProjection_57483842289710_kernel(
    const float* __restrict__ coord,
    const _Float16* __restrict__ ws,
    float* __restrict__ out, int n)
{
    __shared__ float lds[2][GRP * 963];   // 2 x 15408 B

    const int t = threadIdx.x;
    const int ch = 4 * t;
    const _Float16* f; int C, H; float inv;
    if (ch < 64)       { f = ws + ch;                     C = 64;  H = 56; inv = 0.25f;    }
    else if (ch < 192) { f = ws + N56 + (ch - 64);        C = 128; H = 28; inv = 0.125f;   }
    else if (ch < 448) { f = ws + N56+N28 + (ch - 192);   C = 256; H = 14; inv = 0.0625f;  }
    else               { f = ws + N56+N28+N14 + (ch-448); C = 512; H = 7;  inv = 0.03125f; }

    const int p0 = blockIdx.x * PPB;

    // prologue: compute group 0
    compute_group(p0, n, t, ch, coord, f, C, H, inv, lds[0]);
    lds_barrier();

    // steady state: flush group g-1, compute group g under the draining stores
    for (int g = 1; g < NG; ++g) {
        flush_group(lds[(g - 1) & 1], out + (size_t)(p0 + (g - 1) * GRP) * 963, t);
        compute_group(p0 + g * GRP, n, t, ch, coord, f, C, H, inv, lds[g & 1]);
        lds_barrier();
    }

    // epilogue: flush last group (stores drained by hardware at kernel end)
    flush_group(lds[(NG - 1) & 1], out + (size_t)(p0 + (NG - 1) * GRP) * 963, t);
}

// ---- fp32 fallback (round-4 winner) if ws too small ----
__global__ __launch_bounds__(256) void proj_f32_kernel(
    const float* __restrict__ coord,
    const float* __restrict__ f56, const float* __restrict__ f28,
    const float* __restrict__ f14, const float* __restrict__ f7,
    float* __restrict__ out, int n)
{
    const int t = threadIdx.x;
    const int ch = 4 * t;
    const float* f; int C, H; float inv;
    if (ch < 64)       { f = f56 + ch;         C = 64;  H = 56; inv = 0.25f;    }
    else if (ch < 192) { f = f28 + (ch - 64);  C = 128; H = 28; inv = 0.125f;   }
    else if (ch < 448) { f = f14 + (ch - 192); C = 256; H = 14; inv = 0.0625f;  }
    else               { f = f7  + (ch - 448); C = 512; H = 7;  inv = 0.03125f; }
    const int p0 = blockIdx.x * 16, pend = min(p0 + 16, n);
    #pragma unroll 2
    for (int p = p0; p < pend; ++p) {
        float* __restrict__ orow = out + (size_t)p * 963;
        const float X = coord[p*3+0], Y = coord[p*3+1], Z = coord[p*3+2];
        const float rz = 1.0f / (-Z);
        float h = 250.0f * (-Y) * rz + 112.0f;
        float w = 250.0f * X  * rz + 112.0f;
        h = fminf(fmaxf(h, 0.0f), 223.0f);
        w = fminf(fmaxf(w, 0.0f), 223.0f);
        if (t < 240) {
            const float x = h * inv, y = w * inv;
            const float x1 = floorf(x), x2 = ceilf(x);
            const float y1 = floorf(y), y2 = ceilf(y);
            const int xi1 = min(max((int)x1, 0), H - 1);
            const int xi2 = min(max((int)x2, 0), H - 1);
            const int yi1 = min(max((int)y1, 0), H - 1);
            const int yi2 = min(max((int)y2, 0), H - 1);
            const float w11 = (x2-x)*(y2-y), w21 = (x-x1)*(y2-y);
            const float w12 = (x2-x)*(y-y1), w22 = (x-x1)*(y-y1);
            const int r1 = xi1*H, r2 = xi2*H;
            const float4 a = *reinterpret_cast<const float4*>(f + (r1+yi1)*C);
            const float4 b = *reinterpret_cast<const float4*>(f + (r2+yi1)*C);
            const float4 d = *reinterpret_cast<const float4*>(f + (r1+yi2)*C);
            const float4 e = *reinterpret_cast<const float4*>(f + (r2+yi2)*C);
            f4v r;
            r.x = w11*a.x + w21*b.x + w12*d.x + w22*e.x;
            r.y = w11*a.y + w21*b.y + w12*d.y + w22*e.y;
            r.z = w11*a.z + w21*b.z + w12*d.z + w22*e.z;
            r.w = w11*a.w + w21*b.w + w12*d.w + w22*e.w;
            *reinterpret_cast<f4v*>(orow + 3 + ch) = r;
        } else if (t < 243) {
            orow[t - 240] = coord[p*3 + (t-240)];
        }
    }
}

extern "C" void kernel_launch(void* const* d_in, const int* in_sizes, int n_in,
                              void* d_out, int out_size, void* d_ws, size_t ws_size,
                              hipStream_t stream) {
    const float* coord = (const float*)d_in[0];
    const float* f56   = (const float*)d_in[1];
    const float* f28   = (const float*)d_in[2];
    const float* f14   = (const float*)d_in[3];
    const float* f7    = (const float*)d_in[4];
    float* out = (float*)d_out;

    int n = in_sizes[0] / 3;  // 131072 points

    if (ws_size >= (size_t)NTOT * sizeof(_Float16)) {
        _Float16* ws = (_Float16*)d_ws;
        convert_feats_kernel<<<CONV_BLOCKS, 256, 0, stream>>>(f56, f28, f14, f7, ws);
        int grid = (n + PPB - 1) / PPB;  // 16384
        GraphProjection_57483842289710_kernel<<<grid, 256, 0, stream>>>(coord, ws, out, n);
    } else {
        int grid = (n + 15) / 16;
        proj_f32_kernel<<<grid, 256, 0, stream>>>(coord, f56, f28, f14, f7, out, n);
    }
}

// Round 21
// 108.354 us; speedup vs baseline: 1.4423x; 1.0589x over previous
//
#include <hip/hip_runtime.h>

constexpr int PPB = 4;   // points per block (32768 blocks); NG=1 -> single buffer
constexpr int GRP = 4;   // points per LDS buffer (15408 B); ONE buffer = 15.4 KB
                         // -> 8 blocks/CU (32 waves/CU, max occupancy)
constexpr int N56 = 56*56*64;    // 200704
constexpr int N28 = 28*28*128;   // 100352
constexpr int N14 = 14*14*256;   //  50176
constexpr int N7  = 7*7*512;     //  25088
constexpr int NTOT = N56 + N28 + N14 + N7;       // 376320
constexpr int CONV_BLOCKS = (NTOT + 255) / 256;  // 1470

typedef float    f4v __attribute__((ext_vector_type(4)));
typedef _Float16 h4v __attribute__((ext_vector_type(4)));

// LDS-only barrier: drain LDS ops but leave nt stores / gathers in flight.
__device__ __forceinline__ void lds_barrier() {
    asm volatile("s_waitcnt lgkmcnt(0)" ::: "memory");
    __builtin_amdgcn_s_barrier();
    asm volatile("" ::: "memory");
}

// ---- fp32 features -> fp16 in d_ws ----
__global__ __launch_bounds__(256) void convert_feats_kernel(
    const float* __restrict__ f56, const float* __restrict__ f28,
    const float* __restrict__ f14, const float* __restrict__ f7,
    _Float16* __restrict__ ws)
{
    int idx = blockIdx.x * 256 + threadIdx.x;
    if (idx >= NTOT) return;
    float v;
    if (idx < N56)              v = f56[idx];
    else if (idx < N56+N28)     v = f28[idx - N56];
    else if (idx < N56+N28+N14) v = f14[idx - (N56+N28)];
    else                        v = f7[idx - (N56+N28+N14)];
    ws[idx] = (_Float16)v;
}

// compute GRP points' rows into the LDS buffer (this thread's channel quad)
__device__ __forceinline__ void compute_group(
    int pg, int n, int t, int ch,
    const float* __restrict__ coord,
    const _Float16* __restrict__ f, int C, int H, float inv,
    float* __restrict__ buf)
{
    #pragma unroll
    for (int k = 0; k < GRP; ++k) {
        const int p = pg + k;
        if (p >= n) break;

        const float X = coord[p * 3 + 0];
        const float Y = coord[p * 3 + 1];
        const float Z = coord[p * 3 + 2];

        const float rz = 1.0f / (-Z);
        float h = 250.0f * (-Y) * rz + 112.0f;
        float w = 250.0f * X  * rz + 112.0f;
        h = fminf(fmaxf(h, 0.0f), 223.0f);
        w = fminf(fmaxf(w, 0.0f), 223.0f);

        if (t < 240) {
            const float x = h * inv, y = w * inv;
            const float x1 = floorf(x), x2 = ceilf(x);
            const float y1 = floorf(y), y2 = ceilf(y);
            const int xi1 = min(max((int)x1, 0), H - 1);
            const int xi2 = min(max((int)x2, 0), H - 1);
            const int yi1 = min(max((int)y1, 0), H - 1);
            const int yi2 = min(max((int)y2, 0), H - 1);
            const float w11 = (x2 - x) * (y2 - y);
            const float w21 = (x - x1) * (y2 - y);
            const float w12 = (x2 - x) * (y - y1);
            const float w22 = (x - x1) * (y - y1);

            const int r1 = xi1 * H, r2 = xi2 * H;
            const h4v a = *reinterpret_cast<const h4v*>(f + (r1 + yi1) * C);
            const h4v b = *reinterpret_cast<const h4v*>(f + (r2 + yi1) * C);
            const h4v d = *reinterpret_cast<const h4v*>(f + (r1 + yi2) * C);
            const h4v e = *reinterpret_cast<const h4v*>(f + (r2 + yi2) * C);

            float* dst = buf + k * 963 + 3 + ch;
            dst[0] = w11*(float)a.x + w21*(float)b.x + w12*(float)d.x + w22*(float)e.x;
            dst[1] = w11*(float)a.y + w21*(float)b.y + w12*(float)d.y + w22*(float)e.y;
            dst[2] = w11*(float)a.z + w21*(float)b.z + w12*(float)d.z + w22*(float)e.z;
            dst[3] = w11*(float)a.w + w21*(float)b.w + w12*(float)d.w + w22*(float)e.w;
        } else if (t < 243) {
            buf[k * 963 + (t - 240)] = coord[p * 3 + (t - 240)];
        }
    }
}

// flush the buffer (GRP rows, 15408 B contiguous) as aligned nt float4 burst
__device__ __forceinline__ void flush_group(
    const float* __restrict__ buf, float* __restrict__ dst_base, int t)
{
    const f4v* __restrict__ s4 = reinterpret_cast<const f4v*>(buf);
    f4v* __restrict__ d4 = reinterpret_cast<f4v*>(dst_base);
    #pragma unroll
    for (int i = t; i < GRP * 963 / 4; i += 256)   // 963 float4s
        __builtin_nontemporal_store(s4[i], d4 + i);
}

// ---- hot kernel: single-buffer, compute -> barrier -> flush; overlap via
//      8 resident blocks/CU in staggered phases ----
__global__ __launch_bounds__(256) void GraphProjection_57483842289710_kernel(
    const float* __restrict__ coord,
    const _Float16* __restrict__ ws,
    float* __restrict__ out, int n)
{
    __shared__ float lds[GRP * 963];   // 15408 B -> 8 blocks/CU

    const int t = threadIdx.x;
    const int ch = 4 * t;
    const _Float16* f; int C, H; float inv;
    if (ch < 64)       { f = ws + ch;                     C = 64;  H = 56; inv = 0.25f;    }
    else if (ch < 192) { f = ws + N56 + (ch - 64);        C = 128; H = 28; inv = 0.125f;   }
    else if (ch < 448) { f = ws + N56+N28 + (ch - 192);   C = 256; H = 14; inv = 0.0625f;  }
    else               { f = ws + N56+N28+N14 + (ch-448); C = 512; H = 7;  inv = 0.03125f; }

    const int p0 = blockIdx.x * PPB;

    compute_group(p0, n, t, ch, coord, f, C, H, inv, lds);
    lds_barrier();
    flush_group(lds, out + (size_t)p0 * 963, t);
}

// ---- fp32 fallback (round-4 winner) if ws too small ----
__global__ __launch_bounds__(256) void proj_f32_kernel(
    const float* __restrict__ coord,
    const float* __restrict__ f56, const float* __restrict__ f28,
    const float* __restrict__ f14, const float* __restrict__ f7,
    float* __restrict__ out, int n)
{
    const int t = threadIdx.x;
    const int ch = 4 * t;
    const float* f; int C, H; float inv;
    if (ch < 64)       { f = f56 + ch;         C = 64;  H = 56; inv = 0.25f;    }
    else if (ch < 192) { f = f28 + (ch - 64);  C = 128; H = 28; inv = 0.125f;   }
    else if (ch < 448) { f = f14 + (ch - 192); C = 256; H = 14; inv = 0.0625f;  }
    else               { f = f7  + (ch - 448); C = 512; H = 7;  inv = 0.03125f; }
    const int p0 = blockIdx.x * 16, pend = min(p0 + 16, n);
    #pragma unroll 2
    for (int p = p0; p < pend; ++p) {
        float* __restrict__ orow = out + (size_t)p * 963;
        const float X = coord[p*3+0], Y = coord[p*3+1], Z = coord[p*3+2];
        const float rz = 1.0f / (-Z);
        float h = 250.0f * (-Y) * rz + 112.0f;
        float w = 250.0f * X  * rz + 112.0f;
        h = fminf(fmaxf(h, 0.0f), 223.0f);
        w = fminf(fmaxf(w, 0.0f), 223.0f);
        if (t < 240) {
            const float x = h * inv, y = w * inv;
            const float x1 = floorf(x), x2 = ceilf(x);
            const float y1 = floorf(y), y2 = ceilf(y);
            const int xi1 = min(max((int)x1, 0), H - 1);
            const int xi2 = min(max((int)x2, 0), H - 1);
            const int yi1 = min(max((int)y1, 0), H - 1);
            const int yi2 = min(max((int)y2, 0), H - 1);
            const float w11 = (x2-x)*(y2-y), w21 = (x-x1)*(y2-y);
            const float w12 = (x2-x)*(y-y1), w22 = (x-x1)*(y-y1);
            const int r1 = xi1*H, r2 = xi2*H;
            const float4 a = *reinterpret_cast<const float4*>(f + (r1+yi1)*C);
            const float4 b = *reinterpret_cast<const float4*>(f + (r2+yi1)*C);
            const float4 d = *reinterpret_cast<const float4*>(f + (r1+yi2)*C);
            const float4 e = *reinterpret_cast<const float4*>(f + (r2+yi2)*C);
            f4v r;
            r.x = w11*a.x + w21*b.x + w12*d.x + w22*e.x;
            r.y = w11*a.y + w21*b.y + w12*d.y + w22*e.y;
            r.z = w11*a.z + w21*b.z + w12*d.z + w22*e.z;
            r.w = w11*a.w + w21*b.w + w12*d.w + w22*e.w;
            *reinterpret_cast<f4v*>(orow + 3 + ch) = r;
        } else if (t < 243) {
            orow[t - 240] = coord[p*3 + (t-240)];
        }
    }
}

extern "C" void kernel_launch(void* const* d_in, const int* in_sizes, int n_in,
                              void* d_out, int out_size, void* d_ws, size_t ws_size,
                              hipStream_t stream) {
    const float* coord = (const float*)d_in[0];
    const float* f56   = (const float*)d_in[1];
    const float* f28   = (const float*)d_in[2];
    const float* f14   = (const float*)d_in[3];
    const float* f7    = (const float*)d_in[4];
    float* out = (float*)d_out;

    int n = in_sizes[0] / 3;  // 131072 points

    if (ws_size >= (size_t)NTOT * sizeof(_Float16)) {
        _Float16* ws = (_Float16*)d_ws;
        convert_feats_kernel<<<CONV_BLOCKS, 256, 0, stream>>>(f56, f28, f14, f7, ws);
        int grid = (n + PPB - 1) / PPB;  // 32768
        GraphProjection_57483842289710_kernel<<<grid, 256, 0, stream>>>(coord, ws, out, n);
    } else {
        int grid = (n + 15) / 16;
        proj_f32_kernel<<<grid, 256, 0, stream>>>(coord, f56, f28, f14, f7, out, n);
    }
}